// Round 1
// baseline (224.631 us; speedup 1.0000x reference)
//
#include <hip/hip_runtime.h>
#include <hip/hip_bf16.h>

// Problem constants (setup_inputs is fixed: B=4, H=12, L=2048, D=768, K=1024)
#define BB 4
#define HH 12
#define LL 2048
#define DD 768
#define KK 1024

#define ROWS_PER_CHUNK 128
#define CHUNKS ((HH * LL) / ROWS_PER_CHUNK)  // 192

// ---------------------------------------------------------------------------
// Kernel 1: importance partial sums.
// importance_raw[b,l] = sum_{h,q} scores[b,h,q,l] * mask_f[b,q]
// Each block: one batch b, one chunk of 128 (h,q)-rows. 256 threads each own
// 8 columns (two float4 per row, fully coalesced). Accumulate in double,
// flush with hardware f64 atomics (192 colliders/address -> cheap).
// ---------------------------------------------------------------------------
__global__ __launch_bounds__(256) void reduce_kernel(
    const float* __restrict__ scores, const float* __restrict__ amask,
    double* __restrict__ imp)
{
    const int chunk = blockIdx.x;
    const int b     = blockIdx.y;
    const int t     = threadIdx.x;
    const int r0    = chunk * ROWS_PER_CHUNK;          // global row within (H*L)
    const int q0    = r0 & (LL - 1);                   // q of first row (chunk never crosses h)

    __shared__ float w_lds[ROWS_PER_CHUNK];
    if (t < ROWS_PER_CHUNK)
        w_lds[t] = (amask[b * LL + q0 + t] > -10.0f) ? 1.0f : 0.0f;
    __syncthreads();

    double acc[8] = {0, 0, 0, 0, 0, 0, 0, 0};
    const float4* rowbase =
        (const float4*)(scores + (size_t)(b * HH * LL + r0) * LL);

    #pragma unroll 2
    for (int rr = 0; rr < ROWS_PER_CHUNK; ++rr) {
        float w = w_lds[rr];               // uniform across the block
        if (w != 0.0f) {
            const float4* rp = rowbase + (size_t)rr * (LL / 4);
            float4 v0 = rp[t];             // columns 4t .. 4t+3
            float4 v1 = rp[t + 256];       // columns 1024+4t .. 1024+4t+3
            acc[0] += v0.x; acc[1] += v0.y; acc[2] += v0.z; acc[3] += v0.w;
            acc[4] += v1.x; acc[5] += v1.y; acc[6] += v1.z; acc[7] += v1.w;
        }
    }

    double* ip = imp + (size_t)b * LL;
    const int c0 = 4 * t;            // first column group
    const int c1 = 1024 + 4 * t;     // second column group
    unsafeAtomicAdd(&ip[c0 + 0], acc[0]);
    unsafeAtomicAdd(&ip[c0 + 1], acc[1]);
    unsafeAtomicAdd(&ip[c0 + 2], acc[2]);
    unsafeAtomicAdd(&ip[c0 + 3], acc[3]);
    unsafeAtomicAdd(&ip[c1 + 0], acc[4]);
    unsafeAtomicAdd(&ip[c1 + 1], acc[5]);
    unsafeAtomicAdd(&ip[c1 + 2], acc[6]);
    unsafeAtomicAdd(&ip[c1 + 3], acc[7]);
}

// ---------------------------------------------------------------------------
// Kernel 2: per-batch finalize + top-K + index sort + small outputs.
// One 1024-thread block per batch. Bitonic sort of 2048 (val desc, idx asc
// tie-break, matching jax.lax.top_k), then bitonic ascending sort of the K
// selected indices. Also writes preserved_attention_mask and tome_size.
// ---------------------------------------------------------------------------
__global__ __launch_bounds__(1024) void topk_kernel(
    const double* __restrict__ imp, const float* __restrict__ amask,
    int* __restrict__ topk_idx, float* __restrict__ out)
{
    const int b = blockIdx.x;
    const int t = threadIdx.x;

    __shared__ float vals[LL];
    __shared__ int   idxs[LL];

    const double inv = 1.0 / (double)(HH * LL);
    for (int i = t; i < LL; i += 1024) {
        float m = (amask[b * LL + i] > -10.0f) ? 1.0f : 0.0f;
        float v = (float)(imp[b * LL + i] * inv) * m;
        if (i == 0) v = __builtin_inff();
        vals[i] = v;
        idxs[i] = i;
    }
    __syncthreads();

    // Bitonic sort: primary order = descending value, ties -> smaller index.
    for (int k = 2; k <= LL; k <<= 1) {
        for (int j = k >> 1; j > 0; j >>= 1) {
            for (int i = t; i < LL; i += 1024) {
                int ixj = i ^ j;
                if (ixj > i) {
                    bool dir = ((i & k) == 0);   // true => primary order here
                    float va = vals[i], vb = vals[ixj];
                    int   ia = idxs[i], ib = idxs[ixj];
                    // does element at ixj strictly precede element at i?
                    bool ooo = (vb > va) || (vb == va && ib < ia);
                    if (ooo == dir) {
                        vals[i] = vb; vals[ixj] = va;
                        idxs[i] = ib; idxs[ixj] = ia;
                    }
                }
            }
            __syncthreads();
        }
    }

    // Sort the K selected indices ascending (K = KK = 1024, power of two).
    for (int k = 2; k <= KK; k <<= 1) {
        for (int j = k >> 1; j > 0; j >>= 1) {
            for (int i = t; i < KK; i += 1024) {
                int ixj = i ^ j;
                if (ixj > i) {
                    bool dir = ((i & k) == 0);   // true => ascending here
                    int ia = idxs[i], ib = idxs[ixj];
                    bool ooo = (ib < ia);
                    if (ooo == dir) { idxs[i] = ib; idxs[ixj] = ia; }
                }
            }
            __syncthreads();
        }
    }

    // Emit small outputs + index list for gather kernel.
    const size_t tok_sz = (size_t)BB * KK * DD;
    for (int i = t; i < KK; i += 1024) {
        int id = idxs[i];
        topk_idx[b * KK + i] = id;
        out[tok_sz + (size_t)b * KK + i] = amask[b * LL + id];
        out[tok_sz + (size_t)BB * KK + (size_t)b * KK + i] = 1.0f;
    }
}

// ---------------------------------------------------------------------------
// Kernel 3: gather preserved tokens. One block per (b,k) row; 192 threads,
// one float4 each (D=768 floats = 192 float4).
// ---------------------------------------------------------------------------
__global__ __launch_bounds__(192) void gather_kernel(
    const float* __restrict__ hs, const int* __restrict__ topk_idx,
    float* __restrict__ out)
{
    const int k = blockIdx.x;
    const int b = blockIdx.y;
    const int t = threadIdx.x;
    const int id = topk_idx[b * KK + k];
    const float4* src = (const float4*)(hs + (size_t)(b * LL + id) * DD);
    float4*       dst = (float4*)(out + (size_t)(b * KK + k) * DD);
    dst[t] = src[t];
}

extern "C" void kernel_launch(void* const* d_in, const int* in_sizes, int n_in,
                              void* d_out, int out_size, void* d_ws, size_t ws_size,
                              hipStream_t stream) {
    const float* hs     = (const float*)d_in[0];  // (B, L, D)
    const float* amask  = (const float*)d_in[1];  // (B, 1, 1, L)
    const float* scores = (const float*)d_in[2];  // (B, H, L, L)
    float* out = (float*)d_out;

    double* imp  = (double*)d_ws;                                   // B*L doubles = 64 KB
    int*    topk = (int*)((char*)d_ws + (size_t)BB * LL * sizeof(double)); // B*K ints

    hipMemsetAsync(d_ws, 0, (size_t)BB * LL * sizeof(double), stream);

    reduce_kernel<<<dim3(CHUNKS, BB), 256, 0, stream>>>(scores, amask, imp);
    topk_kernel<<<BB, 1024, 0, stream>>>(imp, amask, topk, out);
    gather_kernel<<<dim3(KK, BB), 192, 0, stream>>>(hs, topk, out);
}

// Round 2
// 190.391 us; speedup vs baseline: 1.1798x; 1.1798x over previous
//
#include <hip/hip_runtime.h>
#include <hip/hip_bf16.h>

// Problem constants (setup_inputs is fixed: B=4, H=12, L=2048, D=768, K=1024)
#define BB 4
#define HH 12
#define LL 2048
#define DD 768
#define KK 1024

#define ROWS_PER_CHUNK 128
#define CHUNKS ((HH * LL) / ROWS_PER_CHUNK)  // 192

// ---------------------------------------------------------------------------
// Kernel 1: importance partial sums.
// imp[b,l] = sum_{h,q} scores[b,h,q,l] * mask_f[b,q]   (f64 accumulation)
// Block = (chunk of 128 rows, batch). 256 threads each own 8 fixed columns.
// 2 rows/iter, loads issued before accumulation; w in {0,1} so f32 mult is
// exact. Flush with f64 HW atomics (192 colliders/address).
// ---------------------------------------------------------------------------
__global__ __launch_bounds__(256) void reduce_kernel(
    const float* __restrict__ scores, const float* __restrict__ amask,
    double* __restrict__ imp)
{
    const int chunk = blockIdx.x;
    const int b     = blockIdx.y;
    const int t     = threadIdx.x;
    const int r0    = chunk * ROWS_PER_CHUNK;          // row within (H*L)
    const int q0    = r0 & (LL - 1);                   // chunk never crosses h

    __shared__ float w_lds[ROWS_PER_CHUNK];
    if (t < ROWS_PER_CHUNK)
        w_lds[t] = (amask[b * LL + q0 + t] > -10.0f) ? 1.0f : 0.0f;
    __syncthreads();

    double acc[8] = {0, 0, 0, 0, 0, 0, 0, 0};
    const float4* rowbase =
        (const float4*)(scores + (size_t)(b * HH * LL + r0) * LL);

    #pragma unroll 2
    for (int rr = 0; rr < ROWS_PER_CHUNK; rr += 2) {
        const float w0 = w_lds[rr];
        const float w1 = w_lds[rr + 1];
        const float4* rpA = rowbase + (size_t)rr * (LL / 4);
        const float4* rpB = rpA + (LL / 4);
        float4 a0 = rpA[t];
        float4 a1 = rpA[t + 256];
        float4 b0 = rpB[t];
        float4 b1 = rpB[t + 256];
        acc[0] += a0.x * w0; acc[1] += a0.y * w0;
        acc[2] += a0.z * w0; acc[3] += a0.w * w0;
        acc[4] += a1.x * w0; acc[5] += a1.y * w0;
        acc[6] += a1.z * w0; acc[7] += a1.w * w0;
        acc[0] += b0.x * w1; acc[1] += b0.y * w1;
        acc[2] += b0.z * w1; acc[3] += b0.w * w1;
        acc[4] += b1.x * w1; acc[5] += b1.y * w1;
        acc[6] += b1.z * w1; acc[7] += b1.w * w1;
    }

    double* ip = imp + (size_t)b * LL;
    const int c0 = 4 * t;
    const int c1 = 1024 + 4 * t;
    unsafeAtomicAdd(&ip[c0 + 0], acc[0]);
    unsafeAtomicAdd(&ip[c0 + 1], acc[1]);
    unsafeAtomicAdd(&ip[c0 + 2], acc[2]);
    unsafeAtomicAdd(&ip[c0 + 3], acc[3]);
    unsafeAtomicAdd(&ip[c1 + 0], acc[4]);
    unsafeAtomicAdd(&ip[c1 + 1], acc[5]);
    unsafeAtomicAdd(&ip[c1 + 2], acc[6]);
    unsafeAtomicAdd(&ip[c1 + 3], acc[7]);
}

// Monotonic u64 key: k(a) < k(b)  <=>  a < b  (doubles, incl. +/-inf)
__device__ __forceinline__ unsigned long long dkey(double v) {
    unsigned long long u = (unsigned long long)__double_as_longlong(v);
    return (u & 0x8000000000000000ULL) ? ~u : (u | 0x8000000000000000ULL);
}

// ---------------------------------------------------------------------------
// Kernel 2: exact descending rank of every element (tie -> smaller index).
// Grid (32, B) x 256 threads. Block ranks 64 elements; each element's 2048
// comparisons are split over 4 threads (512 each). Keys LDS-resident.
// ---------------------------------------------------------------------------
__global__ __launch_bounds__(256) void rank_kernel(
    const double* __restrict__ imp, const float* __restrict__ amask,
    int* __restrict__ rank_out)
{
    const int b = blockIdx.y;
    const int t = threadIdx.x;

    __shared__ unsigned long long keys[LL];   // 16 KB
    __shared__ int part[256];

    const double inv = 1.0 / (double)(HH * LL);
    for (int i = t; i < LL; i += 256) {
        double m = (amask[b * LL + i] > -10.0f) ? 1.0 : 0.0;
        double v = imp[b * LL + i] * inv * m;
        if (i == 0) v = __builtin_inf();
        keys[i] = dkey(v);
    }
    __syncthreads();

    const int e  = (blockIdx.x << 6) + (t & 63);   // element this lane ranks
    const int j0 = (t >> 6) * 512;                 // this thread's compare range
    const unsigned long long myk = keys[e];

    int r = 0;
    #pragma unroll 8
    for (int jj = 0; jj < 512; ++jj) {
        const int j = j0 + jj;
        const unsigned long long kj = keys[j];
        r += (kj > myk) || (kj == myk && j < e);
    }
    part[t] = r;
    __syncthreads();

    if (t < 64) {
        int rk = part[t] + part[t + 64] + part[t + 128] + part[t + 192];
        rank_out[b * LL + (blockIdx.x << 6) + t] = rk;
    }
}

// ---------------------------------------------------------------------------
// Kernel 3: compaction. Ranks are a permutation of 0..L-1 -> exactly K kept.
// keep = rank < K; stable (index-ascending) positions via ballot + scan.
// Writes topk_idx, preserved_attention_mask, tome_size.
// ---------------------------------------------------------------------------
__global__ __launch_bounds__(1024) void finalize_kernel(
    const int* __restrict__ rank, const float* __restrict__ amask,
    int* __restrict__ topk_idx, float* __restrict__ out)
{
    const int b    = blockIdx.x;
    const int t    = threadIdx.x;
    const int lane = t & 63;

    __shared__ int cnt[32];
    __shared__ int pre[32];

    bool keep[2]; int lpre[2];
    #pragma unroll
    for (int p = 0; p < 2; ++p) {
        const int i = p * 1024 + t;
        keep[p] = rank[b * LL + i] < KK;
        unsigned long long m = __ballot(keep[p]);
        lpre[p] = __popcll(m & ((1ULL << lane) - 1ULL));
        if (lane == 0) cnt[i >> 6] = __popcll(m);
    }
    __syncthreads();
    if (t == 0) {
        int s = 0;
        for (int c = 0; c < 32; ++c) { pre[c] = s; s += cnt[c]; }
    }
    __syncthreads();

    const size_t tok_sz = (size_t)BB * KK * DD;
    #pragma unroll
    for (int p = 0; p < 2; ++p) {
        const int i = p * 1024 + t;
        if (keep[p]) {
            const int pos = pre[i >> 6] + lpre[p];
            topk_idx[b * KK + pos] = i;
            out[tok_sz + (size_t)b * KK + pos] = amask[b * LL + i];
            out[tok_sz + (size_t)BB * KK + (size_t)b * KK + pos] = 1.0f;
        }
    }
}

// ---------------------------------------------------------------------------
// Kernel 4: gather preserved tokens. One block per (b,k); 192 threads, one
// float4 each (D = 768 floats = 192 float4).
// ---------------------------------------------------------------------------
__global__ __launch_bounds__(192) void gather_kernel(
    const float* __restrict__ hs, const int* __restrict__ topk_idx,
    float* __restrict__ out)
{
    const int k = blockIdx.x;
    const int b = blockIdx.y;
    const int t = threadIdx.x;
    const int id = topk_idx[b * KK + k];
    const float4* src = (const float4*)(hs + (size_t)(b * LL + id) * DD);
    float4*       dst = (float4*)(out + (size_t)(b * KK + k) * DD);
    dst[t] = src[t];
}

extern "C" void kernel_launch(void* const* d_in, const int* in_sizes, int n_in,
                              void* d_out, int out_size, void* d_ws, size_t ws_size,
                              hipStream_t stream) {
    const float* hs     = (const float*)d_in[0];  // (B, L, D)
    const float* amask  = (const float*)d_in[1];  // (B, 1, 1, L)
    const float* scores = (const float*)d_in[2];  // (B, H, L, L)
    float* out = (float*)d_out;

    char* ws = (char*)d_ws;
    double* imp  = (double*)ws;                               // B*L f64  = 64 KB
    int*    rank = (int*)(ws + (size_t)BB * LL * sizeof(double));   // B*L i32 = 32 KB
    int*    topk = (int*)(ws + (size_t)BB * LL * (sizeof(double) + sizeof(int))); // B*K

    hipMemsetAsync(imp, 0, (size_t)BB * LL * sizeof(double), stream);

    reduce_kernel<<<dim3(CHUNKS, BB), 256, 0, stream>>>(scores, amask, imp);
    rank_kernel<<<dim3(LL / 64, BB), 256, 0, stream>>>(imp, amask, rank);
    finalize_kernel<<<BB, 1024, 0, stream>>>(rank, amask, topk, out);
    gather_kernel<<<dim3(KK, BB), 192, 0, stream>>>(hs, topk, out);
}